// Round 9
// baseline (1007.191 us; speedup 1.0000x reference)
//
#include <hip/hip_runtime.h>
#include <stdint.h>

typedef unsigned short ushort_t;
typedef __bf16 bf16x8 __attribute__((ext_vector_type(8)));
typedef float f32x4 __attribute__((ext_vector_type(4)));

// ---- problem constants ----
#define NB   16
#define CIN  256
#define COUT 128
#define HH   128
#define WW   128
#define HP   130
#define WP   130
#define KTAP 9
#define KTOT 2304   // CIN*9

__device__ __forceinline__ ushort_t f2bf(float f) {
  union { float f; uint32_t u; } v; v.f = f;
  uint32_t u = v.u;
  uint32_t r = (u + 0x7fffu + ((u >> 16) & 1u)) >> 16;
  return (ushort_t)r;
}
__device__ __forceinline__ float bf2f(ushort_t b) {
  union { uint32_t u; float f; } v; v.u = ((uint32_t)b) << 16;
  return v.f;
}
__device__ __forceinline__ void gload_lds16(const void* g, void* l) {
  __builtin_amdgcn_global_load_lds((const __attribute__((address_space(1))) void*)g,
                                   (__attribute__((address_space(3))) void*)l, 16, 0, 0);
}

// ---- kernel 1: alpha + sign weights, [tap][o][c] bf16, coalesced writes ----
__global__ void prep_w_kernel(const float* __restrict__ w,
                              ushort_t* __restrict__ sgnW,
                              float* __restrict__ alpha) {
  int o = blockIdx.x, c = threadIdx.x;   // 256 threads = 256 channels
  const float* wo = w + (size_t)o * KTOT + c * 9;
  float s = 0.f;
#pragma unroll
  for (int tap = 0; tap < 9; ++tap) {
    float v = wo[tap];
    s += fabsf(v);
    ushort_t sg = (v > 0.f) ? 0x3F80 : (v < 0.f ? 0xBF80 : 0);
    sgnW[((size_t)tap * COUT + o) * CIN + c] = sg;   // 512B contiguous per tap
  }
  __shared__ float red[4];
  for (int off = 32; off; off >>= 1) s += __shfl_down(s, off, 64);
  if (!(c & 63)) red[c >> 6] = s;
  __syncthreads();
  if (!c) alpha[o] = (red[0] + red[1] + red[2] + red[3]) * (1.f / (float)KTOT);
}

// ---- kernel 1b: zero only the pad borders of xT ----
__global__ void pad_kernel(ushort_t* __restrict__ xT) {
  int blk = blockIdx.x;                 // 16*130
  int b = blk / 130, h = blk - b * 130;
  int t = threadIdx.x;
  uint32_t* row = (uint32_t*)(xT + ((size_t)b * HP + h) * WP * CIN);
  if (h == 0 || h == 129) {
    for (int i = t; i < WP * CIN / 2; i += 256) row[i] = 0;
  } else {
    if (t < 128) row[t] = 0;                          // w = 0 pixel
    else         row[129 * (CIN / 2) + (t - 128)] = 0; // w = 129 pixel
  }
}

// ---- kernel 2: NCHW f32 -> padded NHWC bf16 transpose, 16B stores ----
__global__ void transpose_kernel(const float* __restrict__ x,
                                 ushort_t* __restrict__ xT) {
  int bid = blockIdx.x;
  int ct = bid & 3;          // 4 c-tiles of 64
  int wt = (bid >> 2) & 1;   // 2 w-tiles of 64
  int h  = (bid >> 3) & 127;
  int b  = bid >> 10;
  int c0 = ct * 64, w0 = wt * 64;
  __shared__ float tile[64][65];
  int t = threadIdx.x;
  const float* src = x + (((size_t)b * CIN + c0) * HH + h) * WW + w0;
#pragma unroll 4
  for (int it = 0; it < 16; ++it) {
    int cl = it * 4 + (t >> 6);
    tile[cl][t & 63] = src[(size_t)cl * (HH * WW) + (t & 63)];
  }
  __syncthreads();
  int cb = (t & 7) * 8;        // 8 consecutive channels per lane
  int wl = t >> 3;             // 0..31
#pragma unroll
  for (int wp = 0; wp < 2; ++wp) {
    int w = wp * 32 + wl;
    uint32_t pk[4];
#pragma unroll
    for (int j = 0; j < 4; ++j)
      pk[j] = (uint32_t)f2bf(tile[cb + 2 * j][w]) |
              ((uint32_t)f2bf(tile[cb + 2 * j + 1][w]) << 16);
    size_t idx = ((((size_t)b * HP + h + 1) * WP) + (w0 + w + 1)) * CIN + c0 + cb;
    *(uint4*)(xT + idx) = *(uint4*)pk;   // 16B store, 8 lanes = 128B line
  }
}

// ---- kernel 3: implicit-GEMM conv, BM=256 (h-pair) x BN=128, 8 waves,
//      single-buffer, i0-outer/tap-inner, LDS-staged coalesced epilogue ----
__global__ __launch_bounds__(512, 4) void conv_gemm(
    const ushort_t* __restrict__ xT, const ushort_t* __restrict__ sgnW,
    const float* __restrict__ alpha, const float* __restrict__ mv1,
    const float* __restrict__ pw, const float* __restrict__ mv2,
    const float* __restrict__ scale, float* __restrict__ out) {
  __shared__ __align__(16) char smem[49152];
  ushort_t* As = (ushort_t*)smem;             // 256 rows x 64 ch = 32KB
  ushort_t* Bs = (ushort_t*)(smem + 32768);   // 128 rows x 64 ch = 16KB
  float*    ep = (float*)smem;                // 32KB epilogue chunk (reuse)

  int bid = blockIdx.x;
  int wg = ((bid & 7) << 7) | (bid >> 3);   // XCD swizzle (1024 = 8*128, bijective)
  int b = wg >> 6, hp = wg & 63;
  int h = hp << 1;                          // block covers output rows h, h+1

  int t = threadIdx.x, wv = t >> 6, l = t & 63;
  int wr = wv >> 1, wc = wv & 1;            // 4 M-waves x 2 N-waves, 64x64 tiles

  int crow = l >> 3;              // row within 8-row chunk
  int se = (l & 7) ^ crow;        // pre-swizzled source slot (constant per lane)
  int lg = l >> 4, rA = l & 15;

  f32x4 acc[4][4] = {};

  const ushort_t* xb = xT + ((size_t)b * HP + h) * WP * CIN;

  for (int i0q = 0; i0q < 4; ++i0q) {       // 64-channel slice outer: L2 row reuse
    int i0 = i0q << 6;
#pragma unroll
    for (int tap = 0; tap < 9; ++tap) {     // unrolled: kh/kw compile-time
      const int kh = tap / 3, kw = tap - kh * 3;
      __syncthreads();                      // previous compute done before overwrite
#pragma unroll
      for (int q = 0; q < 4; ++q) {         // A: 32 chunks of 8 rows, 4 per wave
        int ca = wv * 4 + q;
        int m = ca * 8 + crow;              // m = hh*128 + w
        int hh = m >> 7, w = m & 127;
        gload_lds16(xb + ((size_t)(hh + kh) * WP + w + kw) * CIN + i0 + se * 8,
                    (char*)As + ca * 1024);
      }
#pragma unroll
      for (int q = 0; q < 2; ++q) {         // B: 16 chunks, 2 per wave
        int cb = wv * 2 + q;
        int o = cb * 8 + crow;
        gload_lds16(sgnW + ((size_t)tap * COUT + o) * CIN + i0 + se * 8,
                    (char*)Bs + cb * 1024);
      }
      __syncthreads();                      // compiler drains vmcnt before barrier
#pragma unroll
      for (int kk = 0; kk < 2; ++kk) {
        bf16x8 av[4], bv[4];
#pragma unroll
        for (int mi = 0; mi < 4; ++mi) {
          int m = wr * 64 + mi * 16 + rA;
          int slot = (kk * 4 + lg) ^ (m & 7);
          av[mi] = *(const bf16x8*)((const char*)As + m * 128 + slot * 16);
        }
#pragma unroll
        for (int ni = 0; ni < 4; ++ni) {
          int o = wc * 64 + ni * 16 + rA;
          int slot = (kk * 4 + lg) ^ (o & 7);
          bv[ni] = *(const bf16x8*)((const char*)Bs + o * 128 + slot * 16);
        }
#pragma unroll
        for (int mi = 0; mi < 4; ++mi)
#pragma unroll
          for (int ni = 0; ni < 4; ++ni)
            acc[mi][ni] = __builtin_amdgcn_mfma_f32_16x16x32_bf16(av[mi], bv[ni], acc[mi][ni], 0, 0, 0);
      }
    }
  }

  // ---- epilogue: alpha*acc+b1 -> prelu -> +b2 -> +shortcut, then
  //      LDS-staged (swizzled) -> fully coalesced 256B-run stores ----
  float sc0 = scale[0];
  int hh0 = wr >> 1;                         // this thread's h-subrow (uniform)
  const ushort_t* scrow = xT + (((size_t)b * HP + h + hh0 + 1) * WP + 1) * CIN;
  int myChunk = hh0 * 2 + wc;                // chunk = (hh, o-half)

  for (int ch = 0; ch < 4; ++ch) {
    __syncthreads();                         // chunk buffer free
    if (myChunk == ch) {                     // wave-uniform branch
#pragma unroll
      for (int ni = 0; ni < 4; ++ni) {
        int o = wc * 64 + ni * 16 + rA;
        float al = alpha[o], b1 = mv1[o], p = pw[o], b2 = mv2[o];
#pragma unroll
        for (int mi = 0; mi < 4; ++mi) {
#pragma unroll
          for (int r = 0; r < 4; ++r) {
            int m = wr * 64 + mi * 16 + lg * 4 + r;
            int w = m & 127;
            float v = acc[mi][ni][r] * al + b1;
            v = v > 0.f ? v : p * v;
            v += b2;
            v += bf2f(scrow[(size_t)w * CIN + o]) * sc0;
            int slot = (ni * 16 + rA) * 2 + (w & 1);   // 0..127
            int ww2 = w >> 1;                          // 0..63
            ep[slot * 64 + (ww2 ^ (slot & 31))] = v;   // XOR-swizzled
          }
        }
      }
    }
    __syncthreads();                         // chunk written
    int hh = ch >> 1, c = ch & 1;
#pragma unroll
    for (int j = 0; j < 16; ++j) {           // all 512 threads read+store
      int idx = j * 512 + t;
      int ww2 = idx & 63, slot = idx >> 6;   // slot wave-uniform, ww2 = lane
      float v = ep[slot * 64 + (ww2 ^ (slot & 31))];
      int o = c * 64 + (slot >> 1);
      int oc4 = o * 4 + hh * 2 + (slot & 1);
      out[(((size_t)b * 512 + oc4) * 64 + hp) * 64 + ww2] = v;  // 256B runs
    }
  }
}

extern "C" void kernel_launch(void* const* d_in, const int* in_sizes, int n_in,
                              void* d_out, int out_size, void* d_ws, size_t ws_size,
                              hipStream_t stream) {
  const float* x      = (const float*)d_in[0];
  const float* conv_w = (const float*)d_in[1];
  const float* mv1    = (const float*)d_in[2];
  const float* pw     = (const float*)d_in[3];
  const float* mv2    = (const float*)d_in[4];
  const float* scale  = (const float*)d_in[5];
  float* out = (float*)d_out;

  const size_t XT_ELEMS = (size_t)NB * HP * WP * CIN;          // 69,222,400
  ushort_t* xT   = (ushort_t*)d_ws;
  ushort_t* sgnW = xT + XT_ELEMS;                               // 9*128*256
  float*    alpha = (float*)(sgnW + (size_t)KTAP * COUT * CIN);

  prep_w_kernel<<<COUT, 256, 0, stream>>>(conv_w, sgnW, alpha);
  pad_kernel<<<NB * HP, 256, 0, stream>>>(xT);
  transpose_kernel<<<NB * HH * 2 * 4, 256, 0, stream>>>(x, xT);
  conv_gemm<<<NB * HH / 2, 512, 0, stream>>>(xT, sgnW, alpha, mv1, pw, mv2, scale, out);
}

// Round 10
// 779.332 us; speedup vs baseline: 1.2924x; 1.2924x over previous
//
#include <hip/hip_runtime.h>
#include <stdint.h>

typedef unsigned short ushort_t;
typedef __bf16 bf16x8 __attribute__((ext_vector_type(8)));
typedef float f32x4 __attribute__((ext_vector_type(4)));

// ---- problem constants ----
#define NB   16
#define CIN  256
#define COUT 128
#define HH   128
#define WW   128
#define HP   130
#define WP   130
#define KTOT 2304   // CIN*9

__device__ __forceinline__ ushort_t f2bf(float f) {
  union { float f; uint32_t u; } v; v.f = f;
  uint32_t u = v.u;
  uint32_t r = (u + 0x7fffu + ((u >> 16) & 1u)) >> 16;
  return (ushort_t)r;
}
__device__ __forceinline__ float bf2f(ushort_t b) {
  union { uint32_t u; float f; } v; v.u = ((uint32_t)b) << 16;
  return v.f;
}

// ---- kernel 1: alpha + sign weights PRE-PACKED in MFMA fragment order ----
// pk layout: [i0q][tap][kk][ni][lane l][j]  (4*9*2*8*64*8 = 294912 ushorts)
// so one (i0q,tap,kk,ni) fragment is a contiguous 1KB wave-load.
__global__ void prep_w_kernel(const float* __restrict__ w,
                              ushort_t* __restrict__ pk,
                              float* __restrict__ alpha) {
  int o = blockIdx.x, c = threadIdx.x;   // 256 threads = 256 in-channels
  const float* wo = w + (size_t)o * KTOT + c * 9;
  int ni = o >> 4, rA = o & 15;
  int i0q = c >> 6, r6 = c & 63;
  int kk = r6 >> 5, r5 = r6 & 31, lg = r5 >> 3, j = r5 & 7;
  int l = lg * 16 + rA;
  float s = 0.f;
#pragma unroll
  for (int tap = 0; tap < 9; ++tap) {
    float v = wo[tap];
    s += fabsf(v);
    ushort_t sg = (v > 0.f) ? 0x3F80 : (v < 0.f ? 0xBF80 : 0);
    size_t f = ((((size_t)(i0q * 9 + tap) * 2 + kk) * 8 + ni) * 64 + l) * 8 + j;
    pk[f] = sg;
  }
  __shared__ float red[4];
  for (int off = 32; off; off >>= 1) s += __shfl_down(s, off, 64);
  if (!(c & 63)) red[c >> 6] = s;
  __syncthreads();
  if (!c) alpha[o] = (red[0] + red[1] + red[2] + red[3]) * (1.f / (float)KTOT);
}

// ---- kernel 1b: zero only the pad borders of xT ----
__global__ void pad_kernel(ushort_t* __restrict__ xT) {
  int blk = blockIdx.x;                 // 16*130
  int b = blk / 130, h = blk - b * 130;
  int t = threadIdx.x;
  uint32_t* row = (uint32_t*)(xT + ((size_t)b * HP + h) * WP * CIN);
  if (h == 0 || h == 129) {
    for (int i = t; i < WP * CIN / 2; i += 256) row[i] = 0;
  } else {
    if (t < 128) row[t] = 0;                          // w = 0 pixel
    else         row[129 * (CIN / 2) + (t - 128)] = 0; // w = 129 pixel
  }
}

// ---- kernel 2: NCHW f32 -> padded NHWC bf16 transpose, 16B stores ----
__global__ void transpose_kernel(const float* __restrict__ x,
                                 ushort_t* __restrict__ xT) {
  int bid = blockIdx.x;
  int ct = bid & 3;          // 4 c-tiles of 64
  int wt = (bid >> 2) & 1;   // 2 w-tiles of 64
  int h  = (bid >> 3) & 127;
  int b  = bid >> 10;
  int c0 = ct * 64, w0 = wt * 64;
  __shared__ float tile[64][65];
  int t = threadIdx.x;
  const float* src = x + (((size_t)b * CIN + c0) * HH + h) * WW + w0;
#pragma unroll 4
  for (int it = 0; it < 16; ++it) {
    int cl = it * 4 + (t >> 6);
    tile[cl][t & 63] = src[(size_t)cl * (HH * WW) + (t & 63)];
  }
  __syncthreads();
  int cb = (t & 7) * 8;        // 8 consecutive channels per lane
  int wl = t >> 3;             // 0..31
#pragma unroll
  for (int wp = 0; wp < 2; ++wp) {
    int w = wp * 32 + wl;
    uint32_t pkd[4];
#pragma unroll
    for (int j = 0; j < 4; ++j)
      pkd[j] = (uint32_t)f2bf(tile[cb + 2 * j][w]) |
               ((uint32_t)f2bf(tile[cb + 2 * j + 1][w]) << 16);
    size_t idx = ((((size_t)b * HP + h + 1) * WP) + (w0 + w + 1)) * CIN + c0 + cb;
    *(uint4*)(xT + idx) = *(uint4*)pkd;   // 16B store, 8 lanes = 128B line
  }
}

// ---- kernel 3: implicit-GEMM conv, NO LDS / NO BARRIERS in K-loop.
//      Per-wave 32x128 tile; A-frags direct from L2-hot xT, B-frags
//      direct from L1-resident packed weights. Fused epilogue. ----
__global__ __launch_bounds__(256, 3) void conv_gemm(
    const ushort_t* __restrict__ xT, const ushort_t* __restrict__ pk,
    const float* __restrict__ alpha, const float* __restrict__ mv1,
    const float* __restrict__ pw, const float* __restrict__ mv2,
    const float* __restrict__ scale, float* __restrict__ out) {
  int bid = blockIdx.x;
  int wg = ((bid & 7) << 8) | (bid >> 3);   // XCD swizzle (2048 = 8*256, bijective)
  int b = wg >> 7, h = wg & 127;

  int t = threadIdx.x, wv = t >> 6, l = t & 63;
  int lg = l >> 4, rA = l & 15;

  f32x4 acc[2][8] = {};

  // per-lane A base: pixel (wv*32 + rA), k-offset lg*8 within 64-ch slice
  const ushort_t* xb = xT + ((size_t)b * HP + h) * WP * CIN
                          + ((size_t)(wv * 32 + rA)) * CIN + lg * 8;
  // per-lane B base: lane l's 16B within each packed 1KB fragment
  const ushort_t* pB = pk + l * 8;

  for (int i0q = 0; i0q < 4; ++i0q) {
    int i0 = i0q << 6;
    const size_t bq = (size_t)i0q * 9 * 2 * 8 * 512;   // i0q stride in pk
#pragma unroll
    for (int kh = 0; kh < 3; ++kh) {
#pragma unroll
      for (int kw = 0; kw < 3; ++kw) {
        const int tap = kh * 3 + kw;
        const ushort_t* pA = xb + (kh * WP + kw) * CIN + i0;
        const ushort_t* pT = pB + bq + (size_t)tap * 2 * 8 * 512;
#pragma unroll
        for (int kk = 0; kk < 2; ++kk) {
          bf16x8 a0 = *(const bf16x8*)(pA + kk * 32);
          bf16x8 a1 = *(const bf16x8*)(pA + 4096 + kk * 32);
          bf16x8 bv[8];
#pragma unroll
          for (int ni = 0; ni < 8; ++ni)
            bv[ni] = *(const bf16x8*)(pT + (size_t)(kk * 8 + ni) * 512);
#pragma unroll
          for (int ni = 0; ni < 8; ++ni) {
            acc[0][ni] = __builtin_amdgcn_mfma_f32_16x16x32_bf16(a0, bv[ni], acc[0][ni], 0, 0, 0);
            acc[1][ni] = __builtin_amdgcn_mfma_f32_16x16x32_bf16(a1, bv[ni], acc[1][ni], 0, 0, 0);
          }
        }
      }
    }
  }

  // fused epilogue: alpha*acc + b1 -> prelu -> +b2 -> +shortcut -> unshuffle store
  float sc0 = scale[0];
  const ushort_t* scrow = xT + (((size_t)b * HP + h + 1) * WP + 1) * CIN;
  size_t outBase = (((size_t)b * 512 + (h & 1) * 2) * 64 + (h >> 1)) * 64;
#pragma unroll
  for (int ni = 0; ni < 8; ++ni) {
    int o = ni * 16 + rA;
    float al = alpha[o], b1 = mv1[o], p = pw[o], b2 = mv2[o];
#pragma unroll
    for (int mi = 0; mi < 2; ++mi) {
#pragma unroll
      for (int r = 0; r < 4; ++r) {
        int w = wv * 32 + mi * 16 + lg * 4 + r;
        float v = acc[mi][ni][r] * al + b1;
        v = v > 0.f ? v : p * v;
        v += b2;
        v += bf2f(scrow[(size_t)w * CIN + o]) * sc0;
        out[outBase + (size_t)(o * 4 + (w & 1)) * 4096 + (w >> 1)] = v;
      }
    }
  }
}

extern "C" void kernel_launch(void* const* d_in, const int* in_sizes, int n_in,
                              void* d_out, int out_size, void* d_ws, size_t ws_size,
                              hipStream_t stream) {
  const float* x      = (const float*)d_in[0];
  const float* conv_w = (const float*)d_in[1];
  const float* mv1    = (const float*)d_in[2];
  const float* pw     = (const float*)d_in[3];
  const float* mv2    = (const float*)d_in[4];
  const float* scale  = (const float*)d_in[5];
  float* out = (float*)d_out;

  const size_t XT_ELEMS = (size_t)NB * HP * WP * CIN;          // 69,222,400
  const size_t PK_ELEMS = (size_t)4 * 9 * 2 * 8 * 64 * 8;      // 294,912
  ushort_t* xT   = (ushort_t*)d_ws;
  ushort_t* pk   = xT + XT_ELEMS;
  float*    alpha = (float*)(pk + PK_ELEMS);

  prep_w_kernel<<<COUT, 256, 0, stream>>>(conv_w, pk, alpha);
  pad_kernel<<<NB * HP, 256, 0, stream>>>(xT);
  transpose_kernel<<<NB * HH * 2 * 4, 256, 0, stream>>>(x, xT);
  conv_gemm<<<NB * HH, 256, 0, stream>>>(xT, pk, alpha, mv1, pw, mv2, scale, out);
}